// Round 2
// baseline (999.923 us; speedup 1.0000x reference)
//
#include <hip/hip_runtime.h>
#include <hip/hip_bf16.h>

#define N_NODES   100000
#define N_EDGES   1000000
#define N_FEAT    136
#define HIDDEN    64
#define N_CLASSES 2
#define NUM_GRAPHS 512

// ---- degree ----------------------------------------------------------------
__global__ __launch_bounds__(256) void deg_init_kernel(float* __restrict__ dinv) {
    int i = blockIdx.x * 256 + threadIdx.x;
    if (i < N_NODES) dinv[i] = 1.0f;   // self-loop contributes 1
}

__global__ __launch_bounds__(256) void deg_accum_kernel(const int* __restrict__ dst,
                                                        float* __restrict__ dinv) {
    int e = blockIdx.x * 256 + threadIdx.x;
    if (e < N_EDGES) atomicAdd(&dinv[dst[e]], 1.0f);
}

__global__ __launch_bounds__(256) void deg_fin_kernel(float* __restrict__ dinv) {
    int i = blockIdx.x * 256 + threadIdx.x;
    if (i < N_NODES) dinv[i] = rsqrtf(dinv[i]);
}

// ---- t = x @ W1  (136 -> 64) ----------------------------------------------
__global__ __launch_bounds__(256) void mm1_kernel(const float* __restrict__ x,
                                                  const float* __restrict__ W1,
                                                  float* __restrict__ t) {
    __shared__ float Ws[N_FEAT * HIDDEN];   // 34816 B
    __shared__ float xs[4][N_FEAT];
    for (int i = threadIdx.x; i < N_FEAT * HIDDEN; i += 256) Ws[i] = W1[i];
    int n0 = blockIdx.x * 4;
    for (int i = threadIdx.x; i < 4 * N_FEAT; i += 256) {
        int r = i / N_FEAT, c = i % N_FEAT;
        int n = n0 + r;
        xs[r][c] = (n < N_NODES) ? x[(long long)n * N_FEAT + c] : 0.0f;
    }
    __syncthreads();
    int f = threadIdx.x & 63;
    int r = threadIdx.x >> 6;
    int n = n0 + r;
    if (n >= N_NODES) return;
    float acc = 0.0f;
#pragma unroll 8
    for (int k = 0; k < N_FEAT; ++k) acc += xs[r][k] * Ws[k * HIDDEN + f];
    t[n * HIDDEN + f] = acc;
}

// ---- t = h @ W2  (64 -> 64) ------------------------------------------------
__global__ __launch_bounds__(256) void mm2_kernel(const float* __restrict__ h,
                                                  const float* __restrict__ W2,
                                                  float* __restrict__ t) {
    __shared__ float Ws[HIDDEN * HIDDEN];
    for (int i = threadIdx.x; i < HIDDEN * HIDDEN; i += 256) Ws[i] = W2[i];
    __syncthreads();
    int f = threadIdx.x & 63;
    int r = threadIdx.x >> 6;
    int n = blockIdx.x * 4 + r;
    if (n >= N_NODES) return;
    const float* hr = h + n * HIDDEN;
    float acc = 0.0f;
#pragma unroll
    for (int k = 0; k < HIDDEN; ++k) acc += hr[k] * Ws[k * HIDDEN + f];
    t[n * HIDDEN + f] = acc;
}

// ---- edge scatter: agg[dst] += t[src] * dinv[src]*dinv[dst] ----------------
__global__ __launch_bounds__(256) void edge_agg_kernel(const int* __restrict__ src,
                                                       const int* __restrict__ dst,
                                                       const float* __restrict__ dinv,
                                                       const float* __restrict__ t,
                                                       float* __restrict__ agg) {
    int idx = blockIdx.x * 256 + threadIdx.x;     // E*64 = 64M < 2^31
    int e = idx >> 6;
    if (e >= N_EDGES) return;
    int f = idx & 63;
    int s = src[e], d = dst[e];
    float norm = dinv[s] * dinv[d];
    float v = t[s * HIDDEN + f] * norm;
    atomicAdd(&agg[d * HIDDEN + f], v);
}

// ---- h = relu(agg + t*dinv^2 + b), written IN-PLACE into agg ---------------
__global__ __launch_bounds__(256) void brs_kernel(float* __restrict__ agg,
                                                  const float* __restrict__ t,
                                                  const float* __restrict__ dinv,
                                                  const float* __restrict__ b) {
    int idx = blockIdx.x * 256 + threadIdx.x;
    if (idx >= N_NODES * HIDDEN) return;
    int n = idx >> 6, f = idx & 63;
    float di = dinv[n];
    float v = agg[idx] + t[idx] * di * di + b[f];
    agg[idx] = fmaxf(v, 0.0f);
}

// ---- mean pool (atomic) ----------------------------------------------------
__global__ __launch_bounds__(256) void pool_kernel(const float* __restrict__ h,
                                                   const int* __restrict__ batch,
                                                   float* __restrict__ sums,
                                                   float* __restrict__ counts) {
    int idx = blockIdx.x * 256 + threadIdx.x;
    if (idx >= N_NODES * HIDDEN) return;
    int n = idx >> 6, f = idx & 63;
    int g = batch[n];
    atomicAdd(&sums[g * HIDDEN + f], h[idx]);
    if (f == 0) atomicAdd(&counts[g], 1.0f);
}

// ---- head: out = (sums/counts) @ Wout + bout -------------------------------
__global__ __launch_bounds__(256) void out_kernel(const float* __restrict__ sums,
                                                  const float* __restrict__ counts,
                                                  const float* __restrict__ Wout,
                                                  const float* __restrict__ bout,
                                                  float* __restrict__ out) {
    int idx = blockIdx.x * 256 + threadIdx.x;
    if (idx >= NUM_GRAPHS * N_CLASSES) return;
    int g = idx / N_CLASSES, c = idx % N_CLASSES;
    float inv_cnt = 1.0f / fmaxf(counts[g], 1.0f);
    float acc = 0.0f;
#pragma unroll
    for (int k = 0; k < HIDDEN; ++k)
        acc += sums[g * HIDDEN + k] * Wout[k * N_CLASSES + c];
    acc = acc * inv_cnt;   // (sum @ W)/cnt == (sum/cnt) @ W (cnt is per-graph scalar)
    acc += bout[c];
    out[idx] = acc;
}

extern "C" void kernel_launch(void* const* d_in, const int* in_sizes, int n_in,
                              void* d_out, int out_size, void* d_ws, size_t ws_size,
                              hipStream_t stream) {
    const float* x     = (const float*)d_in[0];
    const int*   ei    = (const int*)d_in[1];   // [2, E] flat: row0=src, row1=dst
    const int*   batch = (const int*)d_in[2];
    const float* W1    = (const float*)d_in[3];
    const float* b1    = (const float*)d_in[4];
    const float* W2    = (const float*)d_in[5];
    const float* b2    = (const float*)d_in[6];
    const float* Wout  = (const float*)d_in[7];
    const float* bout  = (const float*)d_in[8];
    float* out = (float*)d_out;

    const int* src = ei;
    const int* dst = ei + N_EDGES;

    // workspace layout (fp32): dinv | bufA | bufB | sums | counts  (~51.7 MB)
    float* ws     = (float*)d_ws;
    const size_t NPAD = 100096;
    float* dinv   = ws;
    float* bufA   = dinv + NPAD;                         // t / t2
    float* bufB   = bufA + (size_t)N_NODES * HIDDEN;     // agg / h (in-place)
    float* sums   = bufB + (size_t)N_NODES * HIDDEN;     // 512*64
    float* counts = sums + NUM_GRAPHS * HIDDEN;          // 512

    const int NB_N  = (N_NODES + 255) / 256;
    const int NB_E  = (N_EDGES + 255) / 256;
    const int NB_NF = (N_NODES * HIDDEN + 255) / 256;    // 25000
    const int NB_EF = (N_EDGES * HIDDEN + 255) / 256;    // 250000
    const int NB_MM = (N_NODES + 3) / 4;                 // 25000

    // degrees -> dinv
    deg_init_kernel<<<NB_N, 256, 0, stream>>>(dinv);
    deg_accum_kernel<<<NB_E, 256, 0, stream>>>(dst, dinv);
    deg_fin_kernel<<<NB_N, 256, 0, stream>>>(dinv);

    hipMemsetAsync(bufB, 0, (size_t)N_NODES * HIDDEN * sizeof(float), stream);
    hipMemsetAsync(sums, 0, (NUM_GRAPHS * HIDDEN + NUM_GRAPHS) * sizeof(float), stream);

    // layer 1: t=x@W1 (A); agg (B); h=relu(...) in-place (B)
    mm1_kernel<<<NB_MM, 256, 0, stream>>>(x, W1, bufA);
    edge_agg_kernel<<<NB_EF, 256, 0, stream>>>(src, dst, dinv, bufA, bufB);
    brs_kernel<<<NB_NF, 256, 0, stream>>>(bufB, bufA, dinv, b1);

    // layer 2: t2=h@W2 (B->A); zero B; agg (B); h2 in-place (B)
    mm2_kernel<<<NB_MM, 256, 0, stream>>>(bufB, W2, bufA);
    hipMemsetAsync(bufB, 0, (size_t)N_NODES * HIDDEN * sizeof(float), stream);
    edge_agg_kernel<<<NB_EF, 256, 0, stream>>>(src, dst, dinv, bufA, bufB);
    brs_kernel<<<NB_NF, 256, 0, stream>>>(bufB, bufA, dinv, b2);

    // pool + head
    pool_kernel<<<NB_NF, 256, 0, stream>>>(bufB, batch, sums, counts);
    out_kernel<<<(NUM_GRAPHS * N_CLASSES + 255) / 256, 256, 0, stream>>>(
        sums, counts, Wout, bout, out);
}

// Round 3
// 592.253 us; speedup vs baseline: 1.6883x; 1.6883x over previous
//
#include <hip/hip_runtime.h>
#include <hip/hip_bf16.h>

#define N_NODES   100000
#define N_EDGES   1000000
#define N_FEAT    136
#define HIDDEN    64
#define N_CLASSES 2
#define NUM_GRAPHS 512

#define NP_PAD    100352          // 98 * 1024
#define SCAN_BLKS 98

// ============================ CSR build =====================================
__global__ __launch_bounds__(256) void hist_kernel(const int* __restrict__ dst,
                                                   int* __restrict__ cnt) {
    int e = blockIdx.x * 256 + threadIdx.x;
    if (e < N_EDGES) atomicAdd(&cnt[dst[e]], 1);
}

// block scans 1024 counts (4/thread), writes block-exclusive scan + partial
__global__ __launch_bounds__(256) void scan1_kernel(const int* __restrict__ cnt,
                                                    int* __restrict__ row_ptr,
                                                    int* __restrict__ partials) {
    __shared__ int sd[256];
    int b = blockIdx.x, t = threadIdx.x;
    int i0 = b * 1024 + t * 4;
    int c0 = (i0 + 0 < N_NODES) ? cnt[i0 + 0] : 0;
    int c1 = (i0 + 1 < N_NODES) ? cnt[i0 + 1] : 0;
    int c2 = (i0 + 2 < N_NODES) ? cnt[i0 + 2] : 0;
    int c3 = (i0 + 3 < N_NODES) ? cnt[i0 + 3] : 0;
    int tsum = c0 + c1 + c2 + c3;
    sd[t] = tsum;
    __syncthreads();
    for (int off = 1; off < 256; off <<= 1) {
        int v = (t >= off) ? sd[t - off] : 0;
        __syncthreads();
        sd[t] += v;
        __syncthreads();
    }
    int excl = sd[t] - tsum;                 // block-exclusive prefix
    row_ptr[i0 + 0] = excl;
    row_ptr[i0 + 1] = excl + c0;
    row_ptr[i0 + 2] = excl + c0 + c1;
    row_ptr[i0 + 3] = excl + c0 + c1 + c2;
    if (t == 255) partials[b] = sd[255];
}

__global__ __launch_bounds__(128) void scan2_kernel(int* __restrict__ partials) {
    __shared__ int sd[128];
    int t = threadIdx.x;
    int v = (t < SCAN_BLKS) ? partials[t] : 0;
    sd[t] = v;
    __syncthreads();
    for (int off = 1; off < 128; off <<= 1) {
        int u = (t >= off) ? sd[t - off] : 0;
        __syncthreads();
        sd[t] += u;
        __syncthreads();
    }
    partials[t] = sd[t] - v;                 // exclusive offsets
}

__global__ __launch_bounds__(256) void scan3_kernel(int* __restrict__ row_ptr,
                                                    int* __restrict__ cursor,
                                                    const int* __restrict__ partials) {
    int i = blockIdx.x * 256 + threadIdx.x;
    if (i < N_NODES) {
        int v = row_ptr[i] + partials[i >> 10];
        row_ptr[i] = v;
        cursor[i]  = v;
    }
    if (i == N_NODES) row_ptr[N_NODES] = N_EDGES;
}

__global__ __launch_bounds__(256) void scatter_kernel(const int* __restrict__ src,
                                                      const int* __restrict__ dst,
                                                      int* __restrict__ cursor,
                                                      int* __restrict__ csr_src) {
    int e = blockIdx.x * 256 + threadIdx.x;
    if (e < N_EDGES) {
        int pos = atomicAdd(&cursor[dst[e]], 1);
        csr_src[pos] = src[e];
    }
}

__global__ __launch_bounds__(256) void dinv_kernel(const int* __restrict__ row_ptr,
                                                   float* __restrict__ dinv) {
    int i = blockIdx.x * 256 + threadIdx.x;
    if (i < N_NODES)
        dinv[i] = rsqrtf((float)(row_ptr[i + 1] - row_ptr[i] + 1));  // +1 self-loop
}

// ==================== t' = (x @ W1) * dinv  (136 -> 64) =====================
// 16 nodes/block, 256 threads, 4 outputs/thread
__global__ __launch_bounds__(256) void mm1_kernel(const float* __restrict__ x,
                                                  const float* __restrict__ W1,
                                                  const float* __restrict__ dinv,
                                                  float* __restrict__ tp) {
    __shared__ float Ws[N_FEAT * HIDDEN];        // [k][f] 34816 B
    __shared__ float4 xs4[16][N_FEAT / 4];       // [n][k/4] 8704 B
    int t = threadIdx.x;
    int n0 = blockIdx.x * 16;                    // 6250*16 = 100000 exact
    {
        const float4* W14 = (const float4*)W1;
        float4* Ws4 = (float4*)Ws;
        for (int i = t; i < N_FEAT * HIDDEN / 4; i += 256) Ws4[i] = W14[i];
        const float4* x4 = (const float4*)x;
        for (int i = t; i < 16 * (N_FEAT / 4); i += 256) {
            int r = i / (N_FEAT / 4), c = i % (N_FEAT / 4);
            xs4[r][c] = x4[(long long)(n0 + r) * (N_FEAT / 4) + c];
        }
    }
    __syncthreads();
    int f = t & 63, w = t >> 6;                  // nodes w, w+4, w+8, w+12
    float a0 = 0.f, a1 = 0.f, a2 = 0.f, a3 = 0.f;
#pragma unroll 2
    for (int k4 = 0; k4 < N_FEAT / 4; ++k4) {
        float w0 = Ws[(4 * k4 + 0) * 64 + f];
        float w1 = Ws[(4 * k4 + 1) * 64 + f];
        float w2 = Ws[(4 * k4 + 2) * 64 + f];
        float w3 = Ws[(4 * k4 + 3) * 64 + f];
        float4 v;
        v = xs4[w][k4];      a0 += v.x * w0 + v.y * w1 + v.z * w2 + v.w * w3;
        v = xs4[w + 4][k4];  a1 += v.x * w0 + v.y * w1 + v.z * w2 + v.w * w3;
        v = xs4[w + 8][k4];  a2 += v.x * w0 + v.y * w1 + v.z * w2 + v.w * w3;
        v = xs4[w + 12][k4]; a3 += v.x * w0 + v.y * w1 + v.z * w2 + v.w * w3;
    }
    tp[(n0 + w) * 64 + f]      = a0 * dinv[n0 + w];
    tp[(n0 + w + 4) * 64 + f]  = a1 * dinv[n0 + w + 4];
    tp[(n0 + w + 8) * 64 + f]  = a2 * dinv[n0 + w + 8];
    tp[(n0 + w + 12) * 64 + f] = a3 * dinv[n0 + w + 12];
}

// ==================== t' = (h @ W2) * dinv  (64 -> 64) ======================
__global__ __launch_bounds__(256) void mm2_kernel(const float* __restrict__ h,
                                                  const float* __restrict__ W2,
                                                  const float* __restrict__ dinv,
                                                  float* __restrict__ tp) {
    __shared__ float Ws[HIDDEN * HIDDEN];        // 16 KB
    __shared__ float4 hs4[16][HIDDEN / 4];       // 4 KB
    int t = threadIdx.x;
    int n0 = blockIdx.x * 16;
    {
        const float4* W24 = (const float4*)W2;
        float4* Ws4 = (float4*)Ws;
        for (int i = t; i < HIDDEN * HIDDEN / 4; i += 256) Ws4[i] = W24[i];
        const float4* h4 = (const float4*)h;
        for (int i = t; i < 16 * (HIDDEN / 4); i += 256) {
            int r = i / (HIDDEN / 4), c = i % (HIDDEN / 4);
            hs4[r][c] = h4[(n0 + r) * (HIDDEN / 4) + c];
        }
    }
    __syncthreads();
    int f = t & 63, w = t >> 6;
    float a0 = 0.f, a1 = 0.f, a2 = 0.f, a3 = 0.f;
#pragma unroll 4
    for (int k4 = 0; k4 < HIDDEN / 4; ++k4) {
        float w0 = Ws[(4 * k4 + 0) * 64 + f];
        float w1 = Ws[(4 * k4 + 1) * 64 + f];
        float w2 = Ws[(4 * k4 + 2) * 64 + f];
        float w3 = Ws[(4 * k4 + 3) * 64 + f];
        float4 v;
        v = hs4[w][k4];      a0 += v.x * w0 + v.y * w1 + v.z * w2 + v.w * w3;
        v = hs4[w + 4][k4];  a1 += v.x * w0 + v.y * w1 + v.z * w2 + v.w * w3;
        v = hs4[w + 8][k4];  a2 += v.x * w0 + v.y * w1 + v.z * w2 + v.w * w3;
        v = hs4[w + 12][k4]; a3 += v.x * w0 + v.y * w1 + v.z * w2 + v.w * w3;
    }
    tp[(n0 + w) * 64 + f]      = a0 * dinv[n0 + w];
    tp[(n0 + w + 4) * 64 + f]  = a1 * dinv[n0 + w + 4];
    tp[(n0 + w + 8) * 64 + f]  = a2 * dinv[n0 + w + 8];
    tp[(n0 + w + 12) * 64 + f] = a3 * dinv[n0 + w + 12];
}

// ========== fused gather-aggregate + self-loop + bias + ReLU (+pool) ========
// one wave per dst node: h[d] = relu(dinv[d]*(sum_{s in N(d)} t'[s] + t'[d]) + b)
__global__ __launch_bounds__(256) void agg_kernel(const int* __restrict__ row_ptr,
                                                  const int* __restrict__ csr_src,
                                                  const float* __restrict__ tp,
                                                  const float* __restrict__ dinv,
                                                  const float* __restrict__ bias,
                                                  float* __restrict__ hout,
                                                  const int* __restrict__ batch,
                                                  float* __restrict__ sums,
                                                  float* __restrict__ gcount,
                                                  int do_pool) {
    int w = threadIdx.x >> 6, f = threadIdx.x & 63;
    int d = blockIdx.x * 4 + w;                  // 25000*4 = 100000 exact
    int row = row_ptr[d], end = row_ptr[d + 1];
    float acc = tp[d * 64 + f];                  // self-loop term
    for (int j0 = row; j0 < end; j0 += 64) {
        int cnt = end - j0; if (cnt > 64) cnt = 64;
        int idx = (f < cnt) ? csr_src[j0 + f] : 0;
        int j = 0;
        for (; j + 4 <= cnt; j += 4) {
            int s0 = __shfl(idx, j),     s1 = __shfl(idx, j + 1);
            int s2 = __shfl(idx, j + 2), s3 = __shfl(idx, j + 3);
            float v0 = tp[s0 * 64 + f], v1 = tp[s1 * 64 + f];
            float v2 = tp[s2 * 64 + f], v3 = tp[s3 * 64 + f];
            acc += v0; acc += v1; acc += v2; acc += v3;
        }
        for (; j < cnt; ++j) {
            int s = __shfl(idx, j);
            acc += tp[s * 64 + f];
        }
    }
    float h = fmaxf(fmaf(dinv[d], acc, bias[f]), 0.0f);
    hout[d * 64 + f] = h;
    if (do_pool) {
        int g = batch[d];
        atomicAdd(&sums[g * 64 + f], h);
        if (f == 0) atomicAdd(&gcount[g], 1.0f);
    }
}

// ---- head: out = (sums/counts) @ Wout + bout -------------------------------
__global__ __launch_bounds__(256) void out_kernel(const float* __restrict__ sums,
                                                  const float* __restrict__ gcount,
                                                  const float* __restrict__ Wout,
                                                  const float* __restrict__ bout,
                                                  float* __restrict__ out) {
    int idx = blockIdx.x * 256 + threadIdx.x;
    if (idx >= NUM_GRAPHS * N_CLASSES) return;
    int g = idx / N_CLASSES, c = idx % N_CLASSES;
    float inv_cnt = 1.0f / fmaxf(gcount[g], 1.0f);
    float acc = 0.0f;
#pragma unroll
    for (int k = 0; k < HIDDEN; ++k)
        acc += sums[g * HIDDEN + k] * Wout[k * N_CLASSES + c];
    out[idx] = acc * inv_cnt + bout[c];
}

extern "C" void kernel_launch(void* const* d_in, const int* in_sizes, int n_in,
                              void* d_out, int out_size, void* d_ws, size_t ws_size,
                              hipStream_t stream) {
    const float* x     = (const float*)d_in[0];
    const int*   ei    = (const int*)d_in[1];
    const int*   batch = (const int*)d_in[2];
    const float* W1    = (const float*)d_in[3];
    const float* b1    = (const float*)d_in[4];
    const float* W2    = (const float*)d_in[5];
    const float* b2    = (const float*)d_in[6];
    const float* Wout  = (const float*)d_in[7];
    const float* bout  = (const float*)d_in[8];
    float* out = (float*)d_out;

    const int* src = ei;
    const int* dst = ei + N_EDGES;

    // -------- workspace layout (~56.6 MB) --------
    char* p = (char*)d_ws;
    int*   row_ptr  = (int*)p;        p += (NP_PAD + 256) * sizeof(int);
    int*   cnt      = (int*)p;        p += NP_PAD * sizeof(int);   // hist, then cursor
    int*   partials = (int*)p;        p += 256 * sizeof(int);
    int*   csr_src  = (int*)p;        p += (size_t)N_EDGES * sizeof(int);
    float* dinv     = (float*)p;      p += NP_PAD * sizeof(float);
    float* bufA     = (float*)p;      p += (size_t)N_NODES * HIDDEN * sizeof(float);
    float* bufB     = (float*)p;      p += (size_t)N_NODES * HIDDEN * sizeof(float);
    float* sums     = (float*)p;      p += NUM_GRAPHS * HIDDEN * sizeof(float);
    float* gcount   = (float*)p;      p += NUM_GRAPHS * sizeof(float);

    const int NB_E  = (N_EDGES + 255) / 256;
    const int NB_N  = (N_NODES + 255) / 256;
    const int NB_MM = N_NODES / 16;          // 6250, exact
    const int NB_AG = N_NODES / 4;           // 25000, exact

    // -------- CSR build --------
    hipMemsetAsync(cnt, 0, NP_PAD * sizeof(int), stream);
    hist_kernel<<<NB_E, 256, 0, stream>>>(dst, cnt);
    scan1_kernel<<<SCAN_BLKS, 256, 0, stream>>>(cnt, row_ptr, partials);
    scan2_kernel<<<1, 128, 0, stream>>>(partials);
    scan3_kernel<<<NP_PAD / 256, 256, 0, stream>>>(row_ptr, cnt, partials);
    scatter_kernel<<<NB_E, 256, 0, stream>>>(src, dst, cnt, csr_src);
    dinv_kernel<<<NB_N, 256, 0, stream>>>(row_ptr, dinv);

    hipMemsetAsync(sums, 0, (NUM_GRAPHS * HIDDEN + NUM_GRAPHS) * sizeof(float), stream);

    // -------- layer 1 --------
    mm1_kernel<<<NB_MM, 256, 0, stream>>>(x, W1, dinv, bufA);
    agg_kernel<<<NB_AG, 256, 0, stream>>>(row_ptr, csr_src, bufA, dinv, b1, bufB,
                                          batch, sums, gcount, 0);
    // -------- layer 2 (pool fused) --------
    mm2_kernel<<<NB_MM, 256, 0, stream>>>(bufB, W2, dinv, bufA);
    agg_kernel<<<NB_AG, 256, 0, stream>>>(row_ptr, csr_src, bufA, dinv, b2, bufB,
                                          batch, sums, gcount, 1);
    // -------- head --------
    out_kernel<<<(NUM_GRAPHS * N_CLASSES + 255) / 256, 256, 0, stream>>>(
        sums, gcount, Wout, bout, out);
}